// Round 4
// baseline (325.203 us; speedup 1.0000x reference)
//
#include <hip/hip_runtime.h>
#include <math.h>

#define D_    100
#define DM_   200
#define DI_   400
#define G4_   1600
#define NN_   200
#define VB_   313   // ceil(5000/16)

__device__ __forceinline__ float sigf(float x){ return 1.0f/(1.0f+__expf(-x)); }
__device__ __forceinline__ unsigned short f2bf(float f){
    unsigned int b = __float_as_uint(f);
    b = (b + 0x7fffu + ((b>>16)&1u)) >> 16;
    return (unsigned short)b;
}
__device__ __forceinline__ float bf_lo(unsigned int w){ return __uint_as_float(w<<16); }
__device__ __forceinline__ float bf_hi(unsigned int w){ return __uint_as_float(w & 0xffff0000u); }

// ---------------------------------------------------------------------------
// Kernel 1: views v3.  grid = 626 (313 rel + 313 ent), 128 thr.
// 16 rows/block, 3 views in parallel; thread = 4 cols x 16 rows.
__global__ __launch_bounds__(128) void views_kernel(
    const float* __restrict__ ent_emb, const float* __restrict__ rel_emb,
    const float* __restrict__ W1, const float* __restrict__ b1,
    const float* __restrict__ W2, const float* __restrict__ b2,
    const float* __restrict__ W3, const float* __restrict__ b3,
    const float* __restrict__ attW1, const float* __restrict__ attW2,
    unsigned short* __restrict__ ent_bf, float* __restrict__ rs_in, float* __restrict__ rs_out)
{
    int bid = blockIdx.x, tid = threadIdx.x;
    bool isRel = bid < VB_;
    int row0 = (isRel ? bid : bid - VB_) * 16;
    int nr = min(16, 5000 - row0);
    const float* src = isRel ? rel_emb : ent_emb;

    __shared__ float eT[D_][16];
    __shared__ float ys[3][16][D_];
    __shared__ float invn[3][16];
    __shared__ float aws[2][D_];

    for (int idx = tid; idx < 400; idx += 128){
        int r = idx / 25, k4 = idx % 25;
        float4 f = make_float4(0.f,0.f,0.f,0.f);
        if (r < nr) f = *(const float4*)(src + (long)(row0+r)*D_ + k4*4);
        eT[k4*4+0][r] = f.x; eT[k4*4+1][r] = f.y; eT[k4*4+2][r] = f.z; eT[k4*4+3][r] = f.w;
    }
    if (isRel){
        for (int idx = tid; idx < 2*D_; idx += 128)
            aws[idx/D_][idx%D_] = (idx < D_) ? attW1[idx] : attW2[idx-D_];
    }
    __syncthreads();

    if (tid < 75){
        int v = tid / 25, q = tid % 25, col0 = q*4;
        const float* Wv = (v==0) ? W1 : (v==1) ? W2 : W3;
        const float* bv = (v==0) ? b1 : (v==1) ? b2 : b3;
        float4 bb = *(const float4*)(bv + col0);
        float acc[16][4];
        #pragma unroll
        for (int r=0;r<16;++r){ acc[r][0]=bb.x; acc[r][1]=bb.y; acc[r][2]=bb.z; acc[r][3]=bb.w; }
        #pragma unroll 2
        for (int k=0;k<D_;++k){
            float4 w = *(const float4*)(Wv + (long)k*D_ + col0);
            const float4* e4 = (const float4*)(&eT[k][0]);
            #pragma unroll
            for (int g=0; g<4; ++g){
                float4 eg = e4[g];
                float ev0=eg.x, ev1=eg.y, ev2=eg.z, ev3=eg.w;
                acc[g*4+0][0]+=ev0*w.x; acc[g*4+0][1]+=ev0*w.y; acc[g*4+0][2]+=ev0*w.z; acc[g*4+0][3]+=ev0*w.w;
                acc[g*4+1][0]+=ev1*w.x; acc[g*4+1][1]+=ev1*w.y; acc[g*4+1][2]+=ev1*w.z; acc[g*4+1][3]+=ev1*w.w;
                acc[g*4+2][0]+=ev2*w.x; acc[g*4+2][1]+=ev2*w.y; acc[g*4+2][2]+=ev2*w.z; acc[g*4+2][3]+=ev2*w.w;
                acc[g*4+3][0]+=ev3*w.x; acc[g*4+3][1]+=ev3*w.y; acc[g*4+3][2]+=ev3*w.z; acc[g*4+3][3]+=ev3*w.w;
            }
        }
        #pragma unroll
        for (int r=0;r<16;++r)
            *(float4*)(&ys[v][r][col0]) = make_float4(acc[r][0],acc[r][1],acc[r][2],acc[r][3]);
    }
    __syncthreads();

    // per-(view,row) inverse norm
    if (tid < 48){
        int v = tid / 16, r = tid % 16;
        float s = 0.f;
        for (int j=0;j<D_;++j){ float t = ys[v][r][j]; s += t*t; }
        invn[v][r] = 1.f / fmaxf(sqrtf(s), 1e-12f);
    }
    __syncthreads();

    if (isRel){
        if (tid < 96){
            int p = tid >> 1, which = tid & 1;
            int v = p / 16, r = p % 16;
            if (r < nr){
                float inv = invn[v][r], s = 0.f;
                for (int j=0;j<D_;++j) s += ys[v][r][j]*aws[which][j];
                (which ? rs_out : rs_in)[(row0+r)*3+v] = s*inv;
            }
        }
    } else {
        for (int idx = tid; idx < 1200; idx += 128){
            int v = idx / 400, rq = idx % 400;
            int r = rq / 25, c0 = (rq % 25)*4;
            if (r < nr){
                float inv = invn[v][r];
                float4 y = *(const float4*)(&ys[v][r][c0]);
                ushort4 o;
                o.x = f2bf(y.x*inv); o.y = f2bf(y.y*inv);
                o.z = f2bf(y.z*inv); o.w = f2bf(y.w*inv);
                *(ushort4*)(ent_bf + ((long)(row0+r)*3+v)*D_ + c0) = o;
            }
        }
    }
}

// ---------------------------------------------------------------------------
// Kernel 2: neigh.  grid = (518, 3), 512 thr. One block per (unit, view).
__global__ __launch_bounds__(512) void neigh_kernel(
    const int* __restrict__ qlc_out, const int* __restrict__ qlc_in,
    const int* __restrict__ qrc_out, const int* __restrict__ qrc_in,
    const int* __restrict__ slc_out, const int* __restrict__ slc_in,
    const int* __restrict__ src_out, const int* __restrict__ src_in,
    const unsigned short* __restrict__ ent_bf, const float* __restrict__ rs_in,
    const float* __restrict__ rs_out,
    float* __restrict__ qn, float* __restrict__ sn)
{
    int u = blockIdx.x, v = blockIdx.y, tid = threadIdx.x;
    const int *cin, *cout; float* dst;
    if      (u < 256){ int n=u;     cout=qlc_out+n*NN_*2; cin=qlc_in+n*NN_*2; dst=qn+n*600;      }
    else if (u < 512){ int n=u-256; cout=qrc_out+n*NN_*2; cin=qrc_in+n*NN_*2; dst=qn+n*600+100;  }
    else if (u < 515){ int n=u-512; cout=slc_out+n*NN_*2; cin=slc_in+n*NN_*2; dst=sn+n*600;      }
    else             { int n=u-515; cout=src_out+n*NN_*2; cin=src_in+n*NN_*2; dst=sn+n*600+100;  }

    __shared__ int   ioff[NN_], ooff[NN_];
    __shared__ float ain[NN_], aout[NN_];
    __shared__ float sv[2][NN_];
    __shared__ float red[512];
    __shared__ float pin[4][D_], pout[4][D_];

    if (tid < NN_){
        int rrel = cin[tid*2], rent = cin[tid*2+1];
        ioff[tid] = (rent*3+v)*D_;
        sv[0][tid] = rs_in[rrel*3+v];
    } else if (tid >= 256 && tid < 256+NN_){
        int k = tid - 256;
        int rrel = cout[k*2], rent = cout[k*2+1];
        ooff[k] = (rent*3+v)*D_;
        sv[1][k] = rs_out[rrel*3+v];
    }
    __syncthreads();

    int half = tid >> 8, l = tid & 255, base = half << 8;
    float x = (l < NN_) ? sv[half][l] : -1e30f;
    red[tid] = x; __syncthreads();
    for (int s = 128; s > 0; s >>= 1){
        if (l < s) red[base+l] = fmaxf(red[base+l], red[base+l+s]);
        __syncthreads();
    }
    float m = red[base]; __syncthreads();
    float e = (l < NN_) ? __expf(x - m) : 0.f;
    red[tid] = e; __syncthreads();
    for (int s = 128; s > 0; s >>= 1){
        if (l < s) red[base+l] += red[base+l+s];
        __syncthreads();
    }
    float S = red[base];
    if (l < NN_){ if (half) aout[l] = e/S; else ain[l] = e/S; }
    __syncthreads();

    int g = tid >> 6, ln = tid & 63;
    if (ln < 50){
        int d0 = ln*2;
        bool isOut = g >= 4;
        int k0 = (g & 3) * 50;
        const int*   offA = isOut ? ooff : ioff;
        const float* aA   = isOut ? aout : ain;
        float acc0 = 0.f, acc1 = 0.f;
        #pragma unroll 5
        for (int kk = 0; kk < 50; ++kk){
            int k = k0 + kk;
            unsigned int w = *(const unsigned int*)(ent_bf + offA[k] + d0);
            float a = aA[k];
            acc0 += a * bf_lo(w);
            acc1 += a * bf_hi(w);
        }
        float2* p = isOut ? (float2*)&pout[g&3][d0] : (float2*)&pin[g&3][d0];
        *p = make_float2(acc0, acc1);
    }
    __syncthreads();

    if (tid < D_){
        float hi = pin[0][tid]+pin[1][tid]+pin[2][tid]+pin[3][tid];
        float ho = pout[0][tid]+pout[1][tid]+pout[2][tid]+pout[3][tid];
        float ea = __expf(hi), ec = __expf(ho);
        dst[v*DM_ + tid] = tanhf((hi*ea + ho*ec)/(ea+ec));
    }
}

// ---------------------------------------------------------------------------
// Kernel 3: senc v3.  grid = 195, 128 thr, 4 rows/block.
__global__ __launch_bounds__(128) void senc_kernel(
    const float* __restrict__ qn, const float* __restrict__ sn,
    const float* __restrict__ seW1, const float* __restrict__ seb1,
    const float* __restrict__ seW2, const float* __restrict__ seb2,
    const float* __restrict__ ln_g, const float* __restrict__ ln_b,
    float* __restrict__ qg, float* __restrict__ sEnc)
{
    int b = blockIdx.x, tid = threadIdx.x;
    int r0 = b*4;

    __shared__ float xsT[DM_][4];
    __shared__ float t1T[DI_][4];
    __shared__ float hv[4][DM_];
    __shared__ float pc[4][DM_];
    __shared__ float mv[4][2];

    for (int idx = tid; idx < 200; idx += 128){
        int rr = idx / 50, j4 = idx % 50;
        int row = r0 + rr;
        float4 f = make_float4(0.f,0.f,0.f,0.f);
        if (row < 777){
            const float* xp = (row < 768) ? qn + (long)(row & 255)*600 + (row >> 8)*DM_
                                          : sn + (long)((row-768)/3)*600 + ((row-768)%3)*DM_;
            f = *(const float4*)(xp + j4*4);
        }
        xsT[j4*4+0][rr]=f.x; xsT[j4*4+1][rr]=f.y; xsT[j4*4+2][rr]=f.z; xsT[j4*4+3][rr]=f.w;
    }
    __syncthreads();

    // phase 1: t1 = relu(x @ seW1 + b1)
    if (tid < 100){
        int col0 = tid*4;
        float4 bb = *(const float4*)(seb1 + col0);
        float a0[4]={bb.x,bb.x,bb.x,bb.x}, a1[4]={bb.y,bb.y,bb.y,bb.y};
        float a2[4]={bb.z,bb.z,bb.z,bb.z}, a3[4]={bb.w,bb.w,bb.w,bb.w};
        #pragma unroll 2
        for (int k=0;k<DM_;++k){
            float4 w = *(const float4*)(seW1 + (long)k*DI_ + col0);
            float4 xq = *(const float4*)(&xsT[k][0]);
            a0[0]+=xq.x*w.x; a0[1]+=xq.y*w.x; a0[2]+=xq.z*w.x; a0[3]+=xq.w*w.x;
            a1[0]+=xq.x*w.y; a1[1]+=xq.y*w.y; a1[2]+=xq.z*w.y; a1[3]+=xq.w*w.y;
            a2[0]+=xq.x*w.z; a2[1]+=xq.y*w.z; a2[2]+=xq.z*w.z; a2[3]+=xq.w*w.z;
            a3[0]+=xq.x*w.w; a3[1]+=xq.y*w.w; a3[2]+=xq.z*w.w; a3[3]+=xq.w*w.w;
        }
        *(float4*)(&t1T[col0+0][0]) = make_float4(fmaxf(a0[0],0.f),fmaxf(a0[1],0.f),fmaxf(a0[2],0.f),fmaxf(a0[3],0.f));
        *(float4*)(&t1T[col0+1][0]) = make_float4(fmaxf(a1[0],0.f),fmaxf(a1[1],0.f),fmaxf(a1[2],0.f),fmaxf(a1[3],0.f));
        *(float4*)(&t1T[col0+2][0]) = make_float4(fmaxf(a2[0],0.f),fmaxf(a2[1],0.f),fmaxf(a2[2],0.f),fmaxf(a2[3],0.f));
        *(float4*)(&t1T[col0+3][0]) = make_float4(fmaxf(a3[0],0.f),fmaxf(a3[1],0.f),fmaxf(a3[2],0.f),fmaxf(a3[3],0.f));
    }
    __syncthreads();

    // phase 2: h = t1 @ seW2 + b2 + x   (K=400 split over 2 groups)
    float acc[4][4] = {};
    int q2 = tid % 50, kg = (tid / 50) & 1, col2 = q2*4;
    if (tid < 100){
        #pragma unroll 2
        for (int kk=0;kk<200;++kk){
            int k = kg*200+kk;
            float4 w = *(const float4*)(seW2 + (long)k*DM_ + col2);
            float4 tq = *(const float4*)(&t1T[k][0]);
            acc[0][0]+=tq.x*w.x; acc[0][1]+=tq.x*w.y; acc[0][2]+=tq.x*w.z; acc[0][3]+=tq.x*w.w;
            acc[1][0]+=tq.y*w.x; acc[1][1]+=tq.y*w.y; acc[1][2]+=tq.y*w.z; acc[1][3]+=tq.y*w.w;
            acc[2][0]+=tq.z*w.x; acc[2][1]+=tq.z*w.y; acc[2][2]+=tq.z*w.z; acc[2][3]+=tq.z*w.w;
            acc[3][0]+=tq.w*w.x; acc[3][1]+=tq.w*w.y; acc[3][2]+=tq.w*w.z; acc[3][3]+=tq.w*w.w;
        }
        if (kg == 1){
            #pragma unroll
            for (int r=0;r<4;++r)
                #pragma unroll
                for (int c=0;c<4;++c) pc[r][col2+c] = acc[r][c];
        }
    }
    __syncthreads();
    if (tid < 50){
        float4 bb = *(const float4*)(seb2 + col2);
        float bbv[4] = {bb.x,bb.y,bb.z,bb.w};
        #pragma unroll
        for (int r=0;r<4;++r){
            #pragma unroll
            for (int c=0;c<4;++c)
                hv[r][col2+c] = acc[r][c] + pc[r][col2+c] + bbv[c] + xsT[col2+c][r];
        }
    }
    __syncthreads();

    // LayerNorm stats: 4 rows x 32 lanes
    {
        int r = tid >> 5, l = tid & 31;
        float s1 = 0.f, s2 = 0.f;
        for (int j = l; j < DM_; j += 32){ float h = hv[r][j]; s1 += h; s2 += h*h; }
        for (int o = 16; o; o >>= 1){ s1 += __shfl_down(s1, o, 32); s2 += __shfl_down(s2, o, 32); }
        if (l == 0){
            float mu = s1 / DM_;
            float var = s2 / DM_ - mu*mu;
            mv[r][0] = mu; mv[r][1] = rsqrtf(var + 1e-5f);
        }
    }
    __syncthreads();

    for (int idx = tid; idx < 4*DM_; idx += 128){
        int rr = idx / DM_, j = idx - rr*DM_;
        int row = r0 + rr;
        if (row < 777){
            float val = ln_g[j]*(hv[rr][j]-mv[rr][0])*mv[rr][1] + ln_b[j];
            if (row < 768) qg[(long)row*DM_ + j] = val;
            else           sEnc[(long)(row-768)*DM_ + j] = val;
        }
    }
}

// ---------------------------------------------------------------------------
// Kernel 4: sw (+ sg).  grid = 75, 64 thr.
__global__ __launch_bounds__(64) void sw_kernel(
    const float* __restrict__ sEnc, const float* __restrict__ Whh,
    float* __restrict__ sg, float* __restrict__ sW)
{
    int b = blockIdx.x, tid = threadIdx.x;
    int s = b / 25, c0 = (b - s*25)*64;
    __shared__ float sgl[DM_];
    for (int j = tid; j < DM_; j += 64){
        float val = (sEnc[s*DM_ + j] + sEnc[(3+s)*DM_ + j] + sEnc[(6+s)*DM_ + j]) * (1.f/3.f);
        sgl[j] = val;
        if (c0 == 0) sg[s*DM_ + j] = val;
    }
    __syncthreads();
    int col = c0 + tid;
    float acc = 0.f;
    for (int i = 0; i < DM_; ++i) acc += sgl[i] * Whh[(long)(DM_+i)*G4_ + col];
    sW[s*G4_ + col] = acc;
}

// ---------------------------------------------------------------------------
// Kernel 5: gemm v4: C[768x1600] = A[768x200] @ B[200x1600] + epilogue.
// tile 32x64, 128 thr, 4x4/thread; A LDS-staged (padded), B straight from L2.
__global__ __launch_bounds__(128) void gemm_kernel(
    const float* __restrict__ A, const float* __restrict__ B,
    const float* __restrict__ qW0, const float* __restrict__ sW,
    const float* __restrict__ alpha,
    const float* __restrict__ bih, const float* __restrict__ bhh,
    float* __restrict__ C, int mode)
{
    int bx = blockIdx.x % 25, by = blockIdx.x / 25;
    int row0 = by*32, col0 = bx*64;
    int tid = threadIdx.x;
    int tx = tid & 15, ty = tid >> 4;
    int cc0 = col0 + tx*4;

    __shared__ float As[50][34];
    __shared__ float alf[32][3];
    if (mode == 1 && tid < 96) alf[tid/3][tid%3] = alpha[(row0 + tid/3)*3 + tid%3];

    float acc[4][4] = {};
    for (int kt = 0; kt < 4; ++kt){
        for (int idx = tid; idx < 800; idx += 128){
            int c2 = idx % 25, r = idx / 25;          // coalesced: c2 fastest
            float2 a2 = *(const float2*)(A + (long)(row0+r)*DM_ + kt*50 + c2*2);
            As[c2*2][r] = a2.x; As[c2*2+1][r] = a2.y;
        }
        __syncthreads();
        const float* Bp = B + (long)kt*50*G4_ + cc0;
        #pragma unroll 2
        for (int k = 0; k < 50; ++k){
            float4 w = *(const float4*)(Bp + (long)k*G4_);
            float2 alo = *(const float2*)(&As[k][ty*4]);
            float2 ahi = *(const float2*)(&As[k][ty*4+2]);
            acc[0][0]+=alo.x*w.x; acc[0][1]+=alo.x*w.y; acc[0][2]+=alo.x*w.z; acc[0][3]+=alo.x*w.w;
            acc[1][0]+=alo.y*w.x; acc[1][1]+=alo.y*w.y; acc[1][2]+=alo.y*w.z; acc[1][3]+=alo.y*w.w;
            acc[2][0]+=ahi.x*w.x; acc[2][1]+=ahi.x*w.y; acc[2][2]+=ahi.x*w.z; acc[2][3]+=ahi.x*w.w;
            acc[3][0]+=ahi.y*w.x; acc[3][1]+=ahi.y*w.y; acc[3][2]+=ahi.y*w.z; acc[3][3]+=ahi.y*w.w;
        }
        __syncthreads();
    }

    if (mode == 0){
        float4 u = *(const float4*)(bih + cc0);
        float4 w = *(const float4*)(bhh + cc0);
        float4 add = make_float4(u.x+w.x, u.y+w.y, u.z+w.z, u.w+w.w);
        #pragma unroll
        for (int r = 0; r < 4; ++r){
            int row = row0 + ty*4 + r;
            float4 o = make_float4(acc[r][0]+add.x, acc[r][1]+add.y, acc[r][2]+add.z, acc[r][3]+add.w);
            *(float4*)(C + (long)row*G4_ + cc0) = o;
        }
    } else {
        float4 s0 = *(const float4*)(sW + 0*G4_ + cc0);
        float4 s1 = *(const float4*)(sW + 1*G4_ + cc0);
        float4 s2 = *(const float4*)(sW + 2*G4_ + cc0);
        #pragma unroll
        for (int r = 0; r < 4; ++r){
            int row = row0 + ty*4 + r;
            float a0 = alf[ty*4+r][0], a1 = alf[ty*4+r][1], a2 = alf[ty*4+r][2];
            float4 qv = *(const float4*)(qW0 + (long)row*G4_ + cc0);
            float4 o;
            o.x = acc[r][0] + qv.x + a0*s0.x + a1*s1.x + a2*s2.x;
            o.y = acc[r][1] + qv.y + a0*s0.y + a1*s1.y + a2*s2.y;
            o.z = acc[r][2] + qv.z + a0*s0.z + a1*s1.z + a2*s2.z;
            o.w = acc[r][3] + qv.w + a0*s0.w + a1*s1.w + a2*s2.w;
            *(float4*)(C + (long)row*G4_ + cc0) = o;
        }
    }
}

// ---------------------------------------------------------------------------
// LSTM cell + support attention. grid 192 x 256 thr, 4 rows/block.
__global__ __launch_bounds__(256) void cell_kernel(
    const float* __restrict__ G, const float* __restrict__ qg,
    const float* __restrict__ sg, float* __restrict__ c,
    float* __restrict__ h, float* __restrict__ alpha, float* __restrict__ sAll,
    int first, int last)
{
    int b = blockIdx.x, tid = threadIdx.x;
    int row0 = b*4;
    __shared__ float hbuf[4][DM_];
    __shared__ float sup[600];
    __shared__ float lg[4][3];

    for (int i = tid; i < 600; i += 256) sup[i] = sg[i];

    for (int idx = tid; idx < 4*DI_; idx += 256){
        int r = idx / DI_, j = idx - r*DI_;
        int row = row0 + r;
        const float* g = G + (long)row*G4_;
        float gi = g[j], gf = g[DI_+j], gg = g[2*DI_+j];
        float cold = first ? 0.f : c[(long)row*DI_ + j];
        float c2 = sigf(gf)*cold + sigf(gi)*tanhf(gg);
        c[(long)row*DI_ + j] = c2;
        if (j < DM_){
            float go = g[3*DI_+j];
            float hval = qg[(long)row*DM_ + j] + sigf(go)*tanhf(c2);
            hbuf[r][j] = hval;
            h[(long)row*DM_ + j] = hval;
        }
    }
    __syncthreads();

    if (!last){
        if (tid < 192){
            int p = tid >> 4, l = tid & 15, r = p/3, s = p - r*3;
            float part = 0.f;
            for (int d = l; d < DM_; d += 16) part += hbuf[r][d]*sup[s*DM_+d];
            for (int o = 8; o; o >>= 1) part += __shfl_down(part, o, 16);
            if (!l) lg[r][s] = part;
        }
        __syncthreads();
        if (tid < 4){
            float l0 = lg[tid][0], l1 = lg[tid][1], l2 = lg[tid][2];
            float m = fmaxf(l0, fmaxf(l1, l2));
            float e0 = __expf(l0-m), e1 = __expf(l1-m), e2 = __expf(l2-m);
            float inv = 1.f/(e0+e1+e2);
            alpha[(row0+tid)*3+0] = e0*inv;
            alpha[(row0+tid)*3+1] = e1*inv;
            alpha[(row0+tid)*3+2] = e2*inv;
        }
    } else {
        int v = row0 >> 8;
        if (tid < 64){
            int r = tid >> 4, l = tid & 15;
            float part = 0.f;
            for (int d = l; d < DM_; d += 16) part += hbuf[r][d]*sup[v*DM_+d];
            for (int o = 8; o; o >>= 1) part += __shfl_down(part, o, 16);
            if (!l) sAll[row0+r] = part;
        }
    }
}

// ---------------------------------------------------------------------------
__global__ void final_kernel(const float* __restrict__ sAll, float* __restrict__ out){
    int n = blockIdx.x*blockDim.x + threadIdx.x;
    if (n < 256) out[n] = fmaxf(sAll[n], fmaxf(sAll[256+n], sAll[512+n]));
}

// ---------------------------------------------------------------------------
extern "C" void kernel_launch(void* const* d_in, const int* in_sizes, int n_in,
                              void* d_out, int out_size, void* d_ws, size_t ws_size,
                              hipStream_t stream)
{
    const float* ent_emb=(const float*)d_in[0];
    const float* rel_emb=(const float*)d_in[1];
    const float* W1=(const float*)d_in[2];  const float* b1=(const float*)d_in[3];
    const float* W2=(const float*)d_in[4];  const float* b2=(const float*)d_in[5];
    const float* W3=(const float*)d_in[6];  const float* b3=(const float*)d_in[7];
    const float* attW1=(const float*)d_in[8];
    const float* attW2=(const float*)d_in[10];
    const float* seW1=(const float*)d_in[12]; const float* seb1=(const float*)d_in[13];
    const float* seW2=(const float*)d_in[14]; const float* seb2=(const float*)d_in[15];
    const float* ln_g=(const float*)d_in[16]; const float* ln_b=(const float*)d_in[17];
    const float* Wih=(const float*)d_in[18];  const float* bih=(const float*)d_in[19];
    const float* Whh=(const float*)d_in[20];  const float* bhh=(const float*)d_in[21];
    const int* qlc_out=(const int*)d_in[24];  const int* qlc_in=(const int*)d_in[25];
    const int* qrc_out=(const int*)d_in[27];  const int* qrc_in=(const int*)d_in[28];
    const int* slc_out=(const int*)d_in[30];  const int* slc_in=(const int*)d_in[31];
    const int* src_out=(const int*)d_in[33];  const int* src_in=(const int*)d_in[34];

    float* ws = (float*)d_ws;
    unsigned short* ent_bf = (unsigned short*)ws;  // 1.5M bf16 (750k float slots)
    float* gates = ws;                 // overlays ent_bf (disjoint lifetime), 1,228,800
    float* rs_in = ws + 1500000;       // 15,000
    float* rs_out= ws + 1515000;       // 15,000
    float* qn    = ws + 1530000;       // 153,600 (dead after senc -> reused as h)
    float* sn    = ws + 1683600;       // 1,800
    float* qg    = ws + 1685400;       // 153,600
    float* sEnc  = ws + 1839000;       // 1,800
    float* sg    = ws + 1840800;       // 600
    float* qW0   = ws + 1841400;       // 1,228,800
    float* cst   = ws + 3070200;       // 307,200
    float* alpha = ws + 3377400;       // 2,304
    float* sW    = ws + 3379704;       // 4,800
    float* sAll  = ws + 3384504;       // 768
    float* h     = qn;                 // 153,600

    views_kernel<<<2*VB_, 128, 0, stream>>>(ent_emb, rel_emb, W1,b1,W2,b2,W3,b3,
                                            attW1, attW2, ent_bf, rs_in, rs_out);
    neigh_kernel<<<dim3(518,3), 512, 0, stream>>>(qlc_out,qlc_in,qrc_out,qrc_in,
                                                  slc_out,slc_in,src_out,src_in,
                                                  ent_bf, rs_in, rs_out, qn, sn);
    senc_kernel<<<195, 128, 0, stream>>>(qn, sn, seW1,seb1,seW2,seb2, ln_g,ln_b, qg, sEnc);
    sw_kernel<<<75, 64, 0, stream>>>(sEnc, Whh, sg, sW);

    gemm_kernel<<<600, 128, 0, stream>>>(qg, Wih, nullptr, nullptr, nullptr,
                                         bih, bhh, qW0, 0);
    cell_kernel<<<192, 256, 0, stream>>>(qW0, qg, sg, cst, h, alpha, sAll, 1, 0);
    for (int s = 1; s < 4; ++s){
        gemm_kernel<<<600, 128, 0, stream>>>(h, Whh, qW0, sW, alpha,
                                             nullptr, nullptr, gates, 1);
        cell_kernel<<<192, 256, 0, stream>>>(gates, qg, sg, cst, h, alpha, sAll,
                                             0, (s==3) ? 1 : 0);
    }
    final_kernel<<<1, 256, 0, stream>>>(sAll, (float*)d_out);
}

// Round 5
// 290.291 us; speedup vs baseline: 1.1203x; 1.1203x over previous
//
#include <hip/hip_runtime.h>
#include <math.h>

#define D_    100
#define DM_   200
#define DI_   400
#define G4_   1600
#define NN_   200

__device__ __forceinline__ float sigf(float x){ return 1.0f/(1.0f+__expf(-x)); }
__device__ __forceinline__ unsigned short f2bf(float f){
    unsigned int b = __float_as_uint(f);
    b = (b + 0x7fffu + ((b>>16)&1u)) >> 16;
    return (unsigned short)b;
}
__device__ __forceinline__ float bf_lo(unsigned int w){ return __uint_as_float(w<<16); }
__device__ __forceinline__ float bf_hi(unsigned int w){ return __uint_as_float(w & 0xffff0000u); }

// ---------------------------------------------------------------------------
// Kernel 1: views v5.  grid = 1250 (625 rel + 625 ent), 128 thr, 8 rows/block.
// e staged as padded float4 blocks: per k4 -> 4 W loads + 8 b128 + 32 FMA.
#define VROWS 8
__global__ __launch_bounds__(128) void views_kernel(
    const float* __restrict__ ent_emb, const float* __restrict__ rel_emb,
    const float* __restrict__ W1, const float* __restrict__ b1,
    const float* __restrict__ W2, const float* __restrict__ b2,
    const float* __restrict__ W3, const float* __restrict__ b3,
    const float* __restrict__ attW1, const float* __restrict__ attW2,
    unsigned short* __restrict__ ent_bf, float* __restrict__ rs_in, float* __restrict__ rs_out)
{
    int bid = blockIdx.x, tid = threadIdx.x;
    bool isRel = bid < 625;
    int row0 = (isRel ? bid : bid - 625) * VROWS;
    const float* src = isRel ? rel_emb : ent_emb;

    __shared__ float4 eT4[25][9];          // padded: bank-spread, 16B-aligned
    __shared__ float  ys[VROWS][D_];
    __shared__ float  invn[VROWS];

    for (int idx = tid; idx < 200; idx += 128){
        int r = idx / 25, c4 = idx % 25;
        eT4[c4][r] = *(const float4*)(src + (long)(row0+r)*D_ + c4*4);
    }
    __syncthreads();

    const float* W[3]  = {W1, W2, W3};
    const float* bb[3] = {b1, b2, b3};

    for (int v = 0; v < 3; ++v){
        if (tid < D_){
            float y[VROWS];
            float bv = bb[v][tid];
            #pragma unroll
            for (int r = 0; r < VROWS; ++r) y[r] = bv;
            const float* Wv = W[v];
            for (int k4 = 0; k4 < 25; ++k4){
                float w0 = Wv[(k4*4+0)*D_ + tid];
                float w1 = Wv[(k4*4+1)*D_ + tid];
                float w2 = Wv[(k4*4+2)*D_ + tid];
                float w3 = Wv[(k4*4+3)*D_ + tid];
                #pragma unroll
                for (int r = 0; r < VROWS; ++r){
                    float4 e = eT4[k4][r];
                    y[r] += e.x*w0 + e.y*w1 + e.z*w2 + e.w*w3;
                }
            }
            #pragma unroll
            for (int r = 0; r < VROWS; ++r) ys[r][tid] = y[r];
        }
        __syncthreads();
        if (tid < VROWS){
            float s = 0.f;
            for (int j = 0; j < D_; ++j){ float t = ys[tid][j]; s += t*t; }
            invn[tid] = 1.f / fmaxf(sqrtf(s), 1e-12f);
        }
        __syncthreads();
        if (isRel){
            if (tid < VROWS){
                float inv = invn[tid], s1 = 0.f, s2 = 0.f;
                for (int j = 0; j < D_; ++j){
                    float t = ys[tid][j] * inv;
                    s1 += t * attW1[j];
                    s2 += t * attW2[j];
                }
                rs_in [(row0+tid)*3 + v] = s1;
                rs_out[(row0+tid)*3 + v] = s2;
            }
        } else {
            for (int idx = tid; idx < 200; idx += 128){
                int r = idx / 25, c0 = (idx % 25)*4;
                float inv = invn[r];
                float4 y4 = *(const float4*)(&ys[r][c0]);
                ushort4 o;
                o.x = f2bf(y4.x*inv); o.y = f2bf(y4.y*inv);
                o.z = f2bf(y4.z*inv); o.w = f2bf(y4.w*inv);
                *(ushort4*)(ent_bf + ((long)(row0+r)*3+v)*D_ + c0) = o;
            }
        }
        __syncthreads();
    }
}

// ---------------------------------------------------------------------------
// Kernel 2: neigh.  grid = (518, 3), 512 thr. Writes contiguous X[784x200].
__global__ __launch_bounds__(512) void neigh_kernel(
    const int* __restrict__ qlc_out, const int* __restrict__ qlc_in,
    const int* __restrict__ qrc_out, const int* __restrict__ qrc_in,
    const int* __restrict__ slc_out, const int* __restrict__ slc_in,
    const int* __restrict__ src_out, const int* __restrict__ src_in,
    const unsigned short* __restrict__ ent_bf, const float* __restrict__ rs_in,
    const float* __restrict__ rs_out,
    float* __restrict__ X)
{
    int u = blockIdx.x, v = blockIdx.y, tid = threadIdx.x;
    const int *cin, *cout; int row, colOff;
    if      (u < 256){ int n=u;     cout=qlc_out+n*NN_*2; cin=qlc_in+n*NN_*2; row=v*256+n;        colOff=0;   }
    else if (u < 512){ int n=u-256; cout=qrc_out+n*NN_*2; cin=qrc_in+n*NN_*2; row=v*256+n;        colOff=100; }
    else if (u < 515){ int f=u-512; cout=slc_out+f*NN_*2; cin=slc_in+f*NN_*2; row=768+f*3+v;      colOff=0;   }
    else             { int f=u-515; cout=src_out+f*NN_*2; cin=src_in+f*NN_*2; row=768+f*3+v;      colOff=100; }

    __shared__ int   ioff[NN_], ooff[NN_];
    __shared__ float ain[NN_], aout[NN_];
    __shared__ float sv[2][NN_];
    __shared__ float red[512];
    __shared__ float pin[4][D_], pout[4][D_];

    if (tid < NN_){
        int rrel = cin[tid*2], rent = cin[tid*2+1];
        ioff[tid] = (rent*3+v)*D_;
        sv[0][tid] = rs_in[rrel*3+v];
    } else if (tid >= 256 && tid < 256+NN_){
        int k = tid - 256;
        int rrel = cout[k*2], rent = cout[k*2+1];
        ooff[k] = (rent*3+v)*D_;
        sv[1][k] = rs_out[rrel*3+v];
    }
    __syncthreads();

    int half = tid >> 8, l = tid & 255, base = half << 8;
    float x = (l < NN_) ? sv[half][l] : -1e30f;
    red[tid] = x; __syncthreads();
    for (int s = 128; s > 0; s >>= 1){
        if (l < s) red[base+l] = fmaxf(red[base+l], red[base+l+s]);
        __syncthreads();
    }
    float m = red[base]; __syncthreads();
    float e = (l < NN_) ? __expf(x - m) : 0.f;
    red[tid] = e; __syncthreads();
    for (int s = 128; s > 0; s >>= 1){
        if (l < s) red[base+l] += red[base+l+s];
        __syncthreads();
    }
    float S = red[base];
    if (l < NN_){ if (half) aout[l] = e/S; else ain[l] = e/S; }
    __syncthreads();

    int g = tid >> 6, ln = tid & 63;
    if (ln < 50){
        int d0 = ln*2;
        bool isOut = g >= 4;
        int k0 = (g & 3) * 50;
        const int*   offA = isOut ? ooff : ioff;
        const float* aA   = isOut ? aout : ain;
        float acc0 = 0.f, acc1 = 0.f;
        #pragma unroll 5
        for (int kk = 0; kk < 50; ++kk){
            int k = k0 + kk;
            unsigned int w = *(const unsigned int*)(ent_bf + offA[k] + d0);
            float a = aA[k];
            acc0 += a * bf_lo(w);
            acc1 += a * bf_hi(w);
        }
        float2* p = isOut ? (float2*)&pout[g&3][d0] : (float2*)&pin[g&3][d0];
        *p = make_float2(acc0, acc1);
    }
    __syncthreads();

    if (tid < D_){
        float hi = pin[0][tid]+pin[1][tid]+pin[2][tid]+pin[3][tid];
        float ho = pout[0][tid]+pout[1][tid]+pout[2][tid]+pout[3][tid];
        float ea = __expf(hi), ec = __expf(ho);
        X[(long)row*DM_ + colOff + tid] = tanhf((hi*ea + ho*ec)/(ea+ec));
    }
}

// ---------------------------------------------------------------------------
// Kernel 3a: seg1 -- T[777x400] = relu(X @ seW1 + b1). grid 25x7=175, 128 thr.
__global__ __launch_bounds__(128) void seg1_kernel(
    const float* __restrict__ X, const float* __restrict__ seW1,
    const float* __restrict__ seb1, float* __restrict__ T)
{
    int bx = blockIdx.x % 7, by = blockIdx.x / 7;
    int row0 = by*32, col0 = bx*64;
    int tid = threadIdx.x, tx = tid & 15, ty = tid >> 4;
    int cc0 = col0 + tx*4;

    __shared__ float As[50][32];
    __shared__ float Bs[50][64];

    float acc[4][4] = {};
    for (int kt = 0; kt < 4; ++kt){
        for (int idx = tid; idx < 800; idx += 128){
            int r = idx & 31, p = idx >> 5;
            int row = row0 + r;
            float2 a2 = make_float2(0.f, 0.f);
            if (row < 777) a2 = *(const float2*)(X + (long)row*DM_ + kt*50 + p*2);
            As[p*2][r] = a2.x; As[p*2+1][r] = a2.y;
        }
        for (int idx = tid; idx < 800; idx += 128){
            int k = idx >> 4, c4 = idx & 15;
            int col = col0 + c4*4;
            float4 f = make_float4(0.f,0.f,0.f,0.f);
            if (col < 400) f = *(const float4*)(seW1 + (long)(kt*50+k)*DI_ + col);
            *(float4*)(&Bs[k][c4*4]) = f;
        }
        __syncthreads();
        #pragma unroll 2
        for (int k = 0; k < 50; ++k){
            float4 a = *(const float4*)(&As[k][ty*4]);
            float4 b = *(const float4*)(&Bs[k][tx*4]);
            acc[0][0]+=a.x*b.x; acc[0][1]+=a.x*b.y; acc[0][2]+=a.x*b.z; acc[0][3]+=a.x*b.w;
            acc[1][0]+=a.y*b.x; acc[1][1]+=a.y*b.y; acc[1][2]+=a.y*b.z; acc[1][3]+=a.y*b.w;
            acc[2][0]+=a.z*b.x; acc[2][1]+=a.z*b.y; acc[2][2]+=a.z*b.z; acc[2][3]+=a.z*b.w;
            acc[3][0]+=a.w*b.x; acc[3][1]+=a.w*b.y; acc[3][2]+=a.w*b.z; acc[3][3]+=a.w*b.w;
        }
        __syncthreads();
    }

    if (cc0 < 400){
        float4 bb = *(const float4*)(seb1 + cc0);
        #pragma unroll
        for (int r = 0; r < 4; ++r){
            int row = row0 + ty*4 + r;
            if (row < 777){
                float4 o = make_float4(fmaxf(acc[r][0]+bb.x,0.f), fmaxf(acc[r][1]+bb.y,0.f),
                                       fmaxf(acc[r][2]+bb.z,0.f), fmaxf(acc[r][3]+bb.w,0.f));
                *(float4*)(T + (long)row*DI_ + cc0) = o;
            }
        }
    }
}

// ---------------------------------------------------------------------------
// Kernel 3b: seg2 -- H[777x200] = T @ seW2 + b2 + X. grid 25x4=100, 128 thr.
__global__ __launch_bounds__(128) void seg2_kernel(
    const float* __restrict__ T, const float* __restrict__ seW2,
    const float* __restrict__ seb2, const float* __restrict__ X,
    float* __restrict__ H)
{
    int bx = blockIdx.x % 4, by = blockIdx.x / 4;
    int row0 = by*32, col0 = bx*64;
    int tid = threadIdx.x, tx = tid & 15, ty = tid >> 4;
    int cc0 = col0 + tx*4;

    __shared__ float As[50][32];
    __shared__ float Bs[50][64];

    float acc[4][4] = {};
    for (int kt = 0; kt < 8; ++kt){
        for (int idx = tid; idx < 800; idx += 128){
            int r = idx & 31, p = idx >> 5;
            int row = row0 + r;
            float2 a2 = make_float2(0.f, 0.f);
            if (row < 777) a2 = *(const float2*)(T + (long)row*DI_ + kt*50 + p*2);
            As[p*2][r] = a2.x; As[p*2+1][r] = a2.y;
        }
        for (int idx = tid; idx < 800; idx += 128){
            int k = idx >> 4, c4 = idx & 15;
            int col = col0 + c4*4;
            float4 f = make_float4(0.f,0.f,0.f,0.f);
            if (col < 200) f = *(const float4*)(seW2 + (long)(kt*50+k)*DM_ + col);
            *(float4*)(&Bs[k][c4*4]) = f;
        }
        __syncthreads();
        #pragma unroll 2
        for (int k = 0; k < 50; ++k){
            float4 a = *(const float4*)(&As[k][ty*4]);
            float4 b = *(const float4*)(&Bs[k][tx*4]);
            acc[0][0]+=a.x*b.x; acc[0][1]+=a.x*b.y; acc[0][2]+=a.x*b.z; acc[0][3]+=a.x*b.w;
            acc[1][0]+=a.y*b.x; acc[1][1]+=a.y*b.y; acc[1][2]+=a.y*b.z; acc[1][3]+=a.y*b.w;
            acc[2][0]+=a.z*b.x; acc[2][1]+=a.z*b.y; acc[2][2]+=a.z*b.z; acc[2][3]+=a.z*b.w;
            acc[3][0]+=a.w*b.x; acc[3][1]+=a.w*b.y; acc[3][2]+=a.w*b.z; acc[3][3]+=a.w*b.w;
        }
        __syncthreads();
    }

    if (cc0 < 200){
        float4 bb = *(const float4*)(seb2 + cc0);
        #pragma unroll
        for (int r = 0; r < 4; ++r){
            int row = row0 + ty*4 + r;
            if (row < 777){
                float4 xr = *(const float4*)(X + (long)row*DM_ + cc0);
                float4 o = make_float4(acc[r][0]+bb.x+xr.x, acc[r][1]+bb.y+xr.y,
                                       acc[r][2]+bb.z+xr.z, acc[r][3]+bb.w+xr.w);
                *(float4*)(H + (long)row*DM_ + cc0) = o;
            }
        }
    }
}

// ---------------------------------------------------------------------------
// Kernel 3c: LayerNorm. grid = 777, 64 thr (one wave per row).
__global__ __launch_bounds__(64) void ln_kernel(
    const float* __restrict__ H, const float* __restrict__ ln_g,
    const float* __restrict__ ln_b, float* __restrict__ qg, float* __restrict__ sEnc)
{
    int row = blockIdx.x, l = threadIdx.x;
    const float* hr = H + (long)row*DM_;
    float v0 = hr[l], v1 = hr[l+64], v2 = hr[l+128];
    float v3 = (l < 8) ? hr[l+192] : 0.f;
    float s1 = v0+v1+v2+v3;
    float s2 = v0*v0+v1*v1+v2*v2+v3*v3;
    #pragma unroll
    for (int o = 32; o; o >>= 1){ s1 += __shfl_down(s1, o); s2 += __shfl_down(s2, o); }
    float mu  = __shfl(s1, 0) * (1.f/DM_);
    float var = __shfl(s2, 0) * (1.f/DM_) - mu*mu;
    float rs  = rsqrtf(var + 1e-5f);
    float* out = (row < 768) ? qg + (long)row*DM_ : sEnc + (long)(row-768)*DM_;
    out[l]     = ln_g[l]    *(v0-mu)*rs + ln_b[l];
    out[l+64]  = ln_g[l+64] *(v1-mu)*rs + ln_b[l+64];
    out[l+128] = ln_g[l+128]*(v2-mu)*rs + ln_b[l+128];
    if (l < 8) out[l+192] = ln_g[l+192]*(v3-mu)*rs + ln_b[l+192];
}

// ---------------------------------------------------------------------------
// Kernel 4: sw (+ sg).  grid = 75, 64 thr.
__global__ __launch_bounds__(64) void sw_kernel(
    const float* __restrict__ sEnc, const float* __restrict__ Whh,
    float* __restrict__ sg, float* __restrict__ sW)
{
    int b = blockIdx.x, tid = threadIdx.x;
    int s = b / 25, c0 = (b - s*25)*64;
    __shared__ float sgl[DM_];
    for (int j = tid; j < DM_; j += 64){
        float val = (sEnc[s*DM_ + j] + sEnc[(3+s)*DM_ + j] + sEnc[(6+s)*DM_ + j]) * (1.f/3.f);
        sgl[j] = val;
        if (c0 == 0) sg[s*DM_ + j] = val;
    }
    __syncthreads();
    int col = c0 + tid;
    float acc = 0.f;
    for (int i = 0; i < DM_; ++i) acc += sgl[i] * Whh[(long)(DM_+i)*G4_ + col];
    sW[s*G4_ + col] = acc;
}

// ---------------------------------------------------------------------------
// Kernel 5: gemm (r3 staged version): C[768x1600] = A[768x200] @ B[200x1600].
// mode 0: += bih+bhh.  mode 1: += qW0 + alpha·sW.  grid 600, 128 thr.
__global__ __launch_bounds__(128) void gemm_kernel(
    const float* __restrict__ A, const float* __restrict__ B,
    const float* __restrict__ qW0, const float* __restrict__ sW,
    const float* __restrict__ alpha,
    const float* __restrict__ bih, const float* __restrict__ bhh,
    float* __restrict__ C, int mode)
{
    int bx = blockIdx.x % 25, by = blockIdx.x / 25;
    int row0 = by*32, col0 = bx*64;
    int tid = threadIdx.x;

    __shared__ float As[50][32];
    __shared__ float Bs[50][64];
    __shared__ float alf[32][3];

    if (mode == 1 && tid < 96) alf[tid/3][tid%3] = alpha[(row0 + tid/3)*3 + tid%3];

    int tx = tid & 15, ty = tid >> 4;
    float acc[4][4] = {};

    for (int kt = 0; kt < 4; ++kt){
        for (int idx = tid; idx < 800; idx += 128){
            int r = idx & 31, p = idx >> 5;
            float2 a2 = *(const float2*)(A + (long)(row0+r)*DM_ + kt*50 + p*2);
            As[p*2][r] = a2.x; As[p*2+1][r] = a2.y;
        }
        for (int idx = tid; idx < 800; idx += 128){
            int k = idx >> 4, c4 = idx & 15;
            *(float4*)(&Bs[k][c4*4]) = *(const float4*)(B + (long)(kt*50+k)*G4_ + col0 + c4*4);
        }
        __syncthreads();
        #pragma unroll 2
        for (int k = 0; k < 50; ++k){
            float4 a = *(const float4*)(&As[k][ty*4]);
            float4 bq = *(const float4*)(&Bs[k][tx*4]);
            acc[0][0]+=a.x*bq.x; acc[0][1]+=a.x*bq.y; acc[0][2]+=a.x*bq.z; acc[0][3]+=a.x*bq.w;
            acc[1][0]+=a.y*bq.x; acc[1][1]+=a.y*bq.y; acc[1][2]+=a.y*bq.z; acc[1][3]+=a.y*bq.w;
            acc[2][0]+=a.z*bq.x; acc[2][1]+=a.z*bq.y; acc[2][2]+=a.z*bq.z; acc[2][3]+=a.z*bq.w;
            acc[3][0]+=a.w*bq.x; acc[3][1]+=a.w*bq.y; acc[3][2]+=a.w*bq.z; acc[3][3]+=a.w*bq.w;
        }
        __syncthreads();
    }

    int cc0 = col0 + tx*4;
    if (mode == 0){
        float4 u = *(const float4*)(bih + cc0);
        float4 w = *(const float4*)(bhh + cc0);
        float4 add = make_float4(u.x+w.x, u.y+w.y, u.z+w.z, u.w+w.w);
        #pragma unroll
        for (int r = 0; r < 4; ++r){
            int row = row0 + ty*4 + r;
            float4 o = make_float4(acc[r][0]+add.x, acc[r][1]+add.y, acc[r][2]+add.z, acc[r][3]+add.w);
            *(float4*)(C + (long)row*G4_ + cc0) = o;
        }
    } else {
        float4 s0 = *(const float4*)(sW + 0*G4_ + cc0);
        float4 s1 = *(const float4*)(sW + 1*G4_ + cc0);
        float4 s2 = *(const float4*)(sW + 2*G4_ + cc0);
        #pragma unroll
        for (int r = 0; r < 4; ++r){
            int row = row0 + ty*4 + r;
            float a0 = alf[ty*4+r][0], a1 = alf[ty*4+r][1], a2 = alf[ty*4+r][2];
            float4 qv = *(const float4*)(qW0 + (long)row*G4_ + cc0);
            float4 o;
            o.x = acc[r][0] + qv.x + a0*s0.x + a1*s1.x + a2*s2.x;
            o.y = acc[r][1] + qv.y + a0*s0.y + a1*s1.y + a2*s2.y;
            o.z = acc[r][2] + qv.z + a0*s0.z + a1*s1.z + a2*s2.z;
            o.w = acc[r][3] + qv.w + a0*s0.w + a1*s1.w + a2*s2.w;
            *(float4*)(C + (long)row*G4_ + cc0) = o;
        }
    }
}

// ---------------------------------------------------------------------------
// LSTM cell + support attention. grid 192 x 256 thr, 4 rows/block.
__global__ __launch_bounds__(256) void cell_kernel(
    const float* __restrict__ G, const float* __restrict__ qg,
    const float* __restrict__ sg, float* __restrict__ c,
    float* __restrict__ h, float* __restrict__ alpha, float* __restrict__ sAll,
    int first, int last)
{
    int b = blockIdx.x, tid = threadIdx.x;
    int row0 = b*4;
    __shared__ float hbuf[4][DM_];
    __shared__ float sup[600];
    __shared__ float lg[4][3];

    for (int i = tid; i < 600; i += 256) sup[i] = sg[i];

    for (int idx = tid; idx < 4*DI_; idx += 256){
        int r = idx / DI_, j = idx - r*DI_;
        int row = row0 + r;
        const float* g = G + (long)row*G4_;
        float gi = g[j], gf = g[DI_+j], gg = g[2*DI_+j];
        float cold = first ? 0.f : c[(long)row*DI_ + j];
        float c2 = sigf(gf)*cold + sigf(gi)*tanhf(gg);
        c[(long)row*DI_ + j] = c2;
        if (j < DM_){
            float go = g[3*DI_+j];
            float hval = qg[(long)row*DM_ + j] + sigf(go)*tanhf(c2);
            hbuf[r][j] = hval;
            h[(long)row*DM_ + j] = hval;
        }
    }
    __syncthreads();

    if (!last){
        if (tid < 192){
            int p = tid >> 4, l = tid & 15, r = p/3, s = p - r*3;
            float part = 0.f;
            for (int d = l; d < DM_; d += 16) part += hbuf[r][d]*sup[s*DM_+d];
            for (int o = 8; o; o >>= 1) part += __shfl_down(part, o, 16);
            if (!l) lg[r][s] = part;
        }
        __syncthreads();
        if (tid < 4){
            float l0 = lg[tid][0], l1 = lg[tid][1], l2 = lg[tid][2];
            float m = fmaxf(l0, fmaxf(l1, l2));
            float e0 = __expf(l0-m), e1 = __expf(l1-m), e2 = __expf(l2-m);
            float inv = 1.f/(e0+e1+e2);
            alpha[(row0+tid)*3+0] = e0*inv;
            alpha[(row0+tid)*3+1] = e1*inv;
            alpha[(row0+tid)*3+2] = e2*inv;
        }
    } else {
        int v = row0 >> 8;
        if (tid < 64){
            int r = tid >> 4, l = tid & 15;
            float part = 0.f;
            for (int d = l; d < DM_; d += 16) part += hbuf[r][d]*sup[v*DM_+d];
            for (int o = 8; o; o >>= 1) part += __shfl_down(part, o, 16);
            if (!l) sAll[row0+r] = part;
        }
    }
}

// ---------------------------------------------------------------------------
__global__ void final_kernel(const float* __restrict__ sAll, float* __restrict__ out){
    int n = blockIdx.x*blockDim.x + threadIdx.x;
    if (n < 256) out[n] = fmaxf(sAll[n], fmaxf(sAll[256+n], sAll[512+n]));
}

// ---------------------------------------------------------------------------
extern "C" void kernel_launch(void* const* d_in, const int* in_sizes, int n_in,
                              void* d_out, int out_size, void* d_ws, size_t ws_size,
                              hipStream_t stream)
{
    const float* ent_emb=(const float*)d_in[0];
    const float* rel_emb=(const float*)d_in[1];
    const float* W1=(const float*)d_in[2];  const float* b1=(const float*)d_in[3];
    const float* W2=(const float*)d_in[4];  const float* b2=(const float*)d_in[5];
    const float* W3=(const float*)d_in[6];  const float* b3=(const float*)d_in[7];
    const float* attW1=(const float*)d_in[8];
    const float* attW2=(const float*)d_in[10];
    const float* seW1=(const float*)d_in[12]; const float* seb1=(const float*)d_in[13];
    const float* seW2=(const float*)d_in[14]; const float* seb2=(const float*)d_in[15];
    const float* ln_g=(const float*)d_in[16]; const float* ln_b=(const float*)d_in[17];
    const float* Wih=(const float*)d_in[18];  const float* bih=(const float*)d_in[19];
    const float* Whh=(const float*)d_in[20];  const float* bhh=(const float*)d_in[21];
    const int* qlc_out=(const int*)d_in[24];  const int* qlc_in=(const int*)d_in[25];
    const int* qrc_out=(const int*)d_in[27];  const int* qrc_in=(const int*)d_in[28];
    const int* slc_out=(const int*)d_in[30];  const int* slc_in=(const int*)d_in[31];
    const int* src_out=(const int*)d_in[33];  const int* src_in=(const int*)d_in[34];

    float* ws = (float*)d_ws;
    // region A (first 1.5M floats), time-multiplexed:
    //   ent_bf (bf16, 750k float-slots): views -> neigh
    //   T      (ws+750000, 313600):      seg1  -> seg2
    //   gates  (ws+0, 1228800):          LSTM steps
    unsigned short* ent_bf = (unsigned short*)ws;
    float* T     = ws + 750000;
    float* gates = ws;
    float* H     = ws + 1063600;       // 156,800 (seg2 -> ln), inside region A tail
    float* rs_in = ws + 1500000;       // 15,000
    float* rs_out= ws + 1515000;       // 15,000
    float* X     = ws + 1530000;       // 156,800 (neigh -> seg2; then reused as h)
    float* qg    = ws + 1686800;       // 153,600
    float* sEnc  = ws + 1840400;       // 1,800
    float* sg    = ws + 1842200;       // 600
    float* qW0   = ws + 1842800;       // 1,228,800
    float* cst   = ws + 3071600;       // 307,200
    float* alpha = ws + 3378800;       // 2,304
    float* sW    = ws + 3381104;       // 4,800
    float* sAll  = ws + 3385904;       // 768
    float* h     = X;                  // X dead after seg2

    views_kernel<<<1250, 128, 0, stream>>>(ent_emb, rel_emb, W1,b1,W2,b2,W3,b3,
                                           attW1, attW2, ent_bf, rs_in, rs_out);
    neigh_kernel<<<dim3(518,3), 512, 0, stream>>>(qlc_out,qlc_in,qrc_out,qrc_in,
                                                  slc_out,slc_in,src_out,src_in,
                                                  ent_bf, rs_in, rs_out, X);
    seg1_kernel<<<175, 128, 0, stream>>>(X, seW1, seb1, T);
    seg2_kernel<<<100, 128, 0, stream>>>(T, seW2, seb2, X, H);
    ln_kernel<<<777, 64, 0, stream>>>(H, ln_g, ln_b, qg, sEnc);
    sw_kernel<<<75, 64, 0, stream>>>(sEnc, Whh, sg, sW);

    gemm_kernel<<<600, 128, 0, stream>>>(qg, Wih, nullptr, nullptr, nullptr,
                                         bih, bhh, qW0, 0);
    cell_kernel<<<192, 256, 0, stream>>>(qW0, qg, sg, cst, h, alpha, sAll, 1, 0);
    for (int s = 1; s < 4; ++s){
        gemm_kernel<<<600, 128, 0, stream>>>(h, Whh, qW0, sW, alpha,
                                             nullptr, nullptr, gates, 1);
        cell_kernel<<<192, 256, 0, stream>>>(gates, qg, sg, cst, h, alpha, sAll,
                                             0, (s==3) ? 1 : 0);
    }
    final_kernel<<<1, 256, 0, stream>>>(sAll, (float*)d_out);
}

// Round 7
// 272.341 us; speedup vs baseline: 1.1941x; 1.0659x over previous
//
#include <hip/hip_runtime.h>
#include <math.h>

#define D_    100
#define DM_   200
#define DI_   400
#define G4_   1600
#define NN_   200

__device__ __forceinline__ float sigf(float x){ return 1.0f/(1.0f+__expf(-x)); }
__device__ __forceinline__ unsigned short f2bf(float f){
    unsigned int b = __float_as_uint(f);
    b = (b + 0x7fffu + ((b>>16)&1u)) >> 16;
    return (unsigned short)b;
}
__device__ __forceinline__ float bf_lo(unsigned int w){ return __uint_as_float(w<<16); }
__device__ __forceinline__ float bf_hi(unsigned int w){ return __uint_as_float(w & 0xffff0000u); }

// ---------------------------------------------------------------------------
// Kernel 1: views v5 (r5 proven).  grid = 1250 (625 rel + 625 ent), 128 thr.
#define VROWS 8
__global__ __launch_bounds__(128) void views_kernel(
    const float* __restrict__ ent_emb, const float* __restrict__ rel_emb,
    const float* __restrict__ W1, const float* __restrict__ b1,
    const float* __restrict__ W2, const float* __restrict__ b2,
    const float* __restrict__ W3, const float* __restrict__ b3,
    const float* __restrict__ attW1, const float* __restrict__ attW2,
    unsigned short* __restrict__ ent_bf, float* __restrict__ rs_in, float* __restrict__ rs_out)
{
    int bid = blockIdx.x, tid = threadIdx.x;
    bool isRel = bid < 625;
    int row0 = (isRel ? bid : bid - 625) * VROWS;
    const float* src = isRel ? rel_emb : ent_emb;

    __shared__ float4 eT4[25][9];          // padded: bank-spread, 16B-aligned
    __shared__ float  ys[VROWS][D_];
    __shared__ float  invn[VROWS];

    for (int idx = tid; idx < 200; idx += 128){
        int r = idx / 25, c4 = idx % 25;
        eT4[c4][r] = *(const float4*)(src + (long)(row0+r)*D_ + c4*4);
    }
    __syncthreads();

    const float* W[3]  = {W1, W2, W3};
    const float* bb[3] = {b1, b2, b3};

    for (int v = 0; v < 3; ++v){
        if (tid < D_){
            float y[VROWS];
            float bv = bb[v][tid];
            #pragma unroll
            for (int r = 0; r < VROWS; ++r) y[r] = bv;
            const float* Wv = W[v];
            for (int k4 = 0; k4 < 25; ++k4){
                float w0 = Wv[(k4*4+0)*D_ + tid];
                float w1 = Wv[(k4*4+1)*D_ + tid];
                float w2 = Wv[(k4*4+2)*D_ + tid];
                float w3 = Wv[(k4*4+3)*D_ + tid];
                #pragma unroll
                for (int r = 0; r < VROWS; ++r){
                    float4 e = eT4[k4][r];
                    y[r] += e.x*w0 + e.y*w1 + e.z*w2 + e.w*w3;
                }
            }
            #pragma unroll
            for (int r = 0; r < VROWS; ++r) ys[r][tid] = y[r];
        }
        __syncthreads();
        if (tid < VROWS){
            float s = 0.f;
            for (int j = 0; j < D_; ++j){ float t = ys[tid][j]; s += t*t; }
            invn[tid] = 1.f / fmaxf(sqrtf(s), 1e-12f);
        }
        __syncthreads();
        if (isRel){
            if (tid < VROWS){
                float inv = invn[tid], s1 = 0.f, s2 = 0.f;
                for (int j = 0; j < D_; ++j){
                    float t = ys[tid][j] * inv;
                    s1 += t * attW1[j];
                    s2 += t * attW2[j];
                }
                rs_in [(row0+tid)*3 + v] = s1;
                rs_out[(row0+tid)*3 + v] = s2;
            }
        } else {
            for (int idx = tid; idx < 200; idx += 128){
                int r = idx / 25, c0 = (idx % 25)*4;
                float inv = invn[r];
                float4 y4 = *(const float4*)(&ys[r][c0]);
                ushort4 o;
                o.x = f2bf(y4.x*inv); o.y = f2bf(y4.y*inv);
                o.z = f2bf(y4.z*inv); o.w = f2bf(y4.w*inv);
                *(ushort4*)(ent_bf + ((long)(row0+r)*3+v)*D_ + c0) = o;
            }
        }
        __syncthreads();
    }
}

// ---------------------------------------------------------------------------
// Kernel 2: neigh (r5 proven tree-softmax).  grid = (518, 3), 512 thr.
__global__ __launch_bounds__(512) void neigh_kernel(
    const int* __restrict__ qlc_out, const int* __restrict__ qlc_in,
    const int* __restrict__ qrc_out, const int* __restrict__ qrc_in,
    const int* __restrict__ slc_out, const int* __restrict__ slc_in,
    const int* __restrict__ src_out, const int* __restrict__ src_in,
    const unsigned short* __restrict__ ent_bf, const float* __restrict__ rs_in,
    const float* __restrict__ rs_out,
    float* __restrict__ X)
{
    int u = blockIdx.x, v = blockIdx.y, tid = threadIdx.x;
    const int *cin, *cout; int row, colOff;
    if      (u < 256){ int n=u;     cout=qlc_out+n*NN_*2; cin=qlc_in+n*NN_*2; row=v*256+n;   colOff=0;   }
    else if (u < 512){ int n=u-256; cout=qrc_out+n*NN_*2; cin=qrc_in+n*NN_*2; row=v*256+n;   colOff=100; }
    else if (u < 515){ int f=u-512; cout=slc_out+f*NN_*2; cin=slc_in+f*NN_*2; row=768+f*3+v; colOff=0;   }
    else             { int f=u-515; cout=src_out+f*NN_*2; cin=src_in+f*NN_*2; row=768+f*3+v; colOff=100; }

    __shared__ int   ioff[NN_], ooff[NN_];
    __shared__ float ain[NN_], aout[NN_];
    __shared__ float sv[2][NN_];
    __shared__ float red[512];
    __shared__ float pin[4][D_], pout[4][D_];

    if (tid < NN_){
        int rrel = cin[tid*2], rent = cin[tid*2+1];
        ioff[tid] = (rent*3+v)*D_;
        sv[0][tid] = rs_in[rrel*3+v];
    } else if (tid >= 256 && tid < 256+NN_){
        int k = tid - 256;
        int rrel = cout[k*2], rent = cout[k*2+1];
        ooff[k] = (rent*3+v)*D_;
        sv[1][k] = rs_out[rrel*3+v];
    }
    __syncthreads();

    // dual tree softmax: half 0 = in, half 1 = out
    int half = tid >> 8, l = tid & 255, base = half << 8;
    float x = (l < NN_) ? sv[half][l] : -1e30f;
    red[tid] = x; __syncthreads();
    for (int s = 128; s > 0; s >>= 1){
        if (l < s) red[base+l] = fmaxf(red[base+l], red[base+l+s]);
        __syncthreads();
    }
    float m = red[base]; __syncthreads();
    float e = (l < NN_) ? __expf(x - m) : 0.f;
    red[tid] = e; __syncthreads();
    for (int s = 128; s > 0; s >>= 1){
        if (l < s) red[base+l] += red[base+l+s];
        __syncthreads();
    }
    float S = red[base];
    if (l < NN_){ if (half) aout[l] = e/S; else ain[l] = e/S; }
    __syncthreads();

    int g = tid >> 6, ln = tid & 63;
    if (ln < 50){
        int d0 = ln*2;
        bool isOut = g >= 4;
        int k0 = (g & 3) * 50;
        const int*   offA = isOut ? ooff : ioff;
        const float* aA   = isOut ? aout : ain;
        float acc0 = 0.f, acc1 = 0.f;
        #pragma unroll 5
        for (int kk = 0; kk < 50; ++kk){
            int k = k0 + kk;
            unsigned int w = *(const unsigned int*)(ent_bf + offA[k] + d0);
            float a = aA[k];
            acc0 += a * bf_lo(w);
            acc1 += a * bf_hi(w);
        }
        float2* p = isOut ? (float2*)&pout[g&3][d0] : (float2*)&pin[g&3][d0];
        *p = make_float2(acc0, acc1);
    }
    __syncthreads();

    if (tid < D_){
        float hi = pin[0][tid]+pin[1][tid]+pin[2][tid]+pin[3][tid];
        float ho = pout[0][tid]+pout[1][tid]+pout[2][tid]+pout[3][tid];
        float ea = __expf(hi), ec = __expf(ho);
        X[(long)row*DM_ + colOff + tid] = tanhf((hi*ea + ho*ec)/(ea+ec));
    }
}

// ---------------------------------------------------------------------------
// Kernel 3: senc fused (MLP + residual + LayerNorm). grid = 98, 512 thr, 8 rows.
// T (400x8) stays in LDS; weights streamed coalesced from L2; no K-phases.
__global__ __launch_bounds__(512) void senc_kernel(
    const float* __restrict__ X,
    const float* __restrict__ seW1, const float* __restrict__ seb1,
    const float* __restrict__ seW2, const float* __restrict__ seb2,
    const float* __restrict__ ln_g, const float* __restrict__ ln_b,
    float* __restrict__ qg, float* __restrict__ sEnc)
{
    int b = blockIdx.x, tid = threadIdx.x;
    int r0 = b*8;

    __shared__ float xT[DM_][12];   // [k][r], pad 12 (16B-aligned, bank-spread)
    __shared__ float tT[DI_][12];   // [k][r]
    __shared__ float hv[8][DM_];
    __shared__ float mv[8][2];

    for (int idx = tid; idx < 1600; idx += 512){
        int r = idx / DM_, k = idx - r*DM_;            // coalesced global
        int row = r0 + r;
        xT[k][r] = (row < 777) ? X[(long)row*DM_ + k] : 0.f;
    }
    __syncthreads();

    // phase 1: T = relu(X @ seW1 + b1), thread = one of 400 cols
    if (tid < DI_){
        int col = tid;
        float acc[8];
        float bb = seb1[col];
        #pragma unroll
        for (int r=0;r<8;++r) acc[r] = bb;
        #pragma unroll 4
        for (int k=0;k<DM_;++k){
            float w = seW1[(long)k*DI_ + col];         // coalesced 1600B
            float4 e0 = *(const float4*)(&xT[k][0]);   // broadcast
            float4 e1 = *(const float4*)(&xT[k][4]);
            acc[0]+=e0.x*w; acc[1]+=e0.y*w; acc[2]+=e0.z*w; acc[3]+=e0.w*w;
            acc[4]+=e1.x*w; acc[5]+=e1.y*w; acc[6]+=e1.z*w; acc[7]+=e1.w*w;
        }
        float4 t0 = make_float4(fmaxf(acc[0],0.f),fmaxf(acc[1],0.f),fmaxf(acc[2],0.f),fmaxf(acc[3],0.f));
        float4 t1 = make_float4(fmaxf(acc[4],0.f),fmaxf(acc[5],0.f),fmaxf(acc[6],0.f),fmaxf(acc[7],0.f));
        *(float4*)(&tT[col][0]) = t0;
        *(float4*)(&tT[col][4]) = t1;
    }
    __syncthreads();

    // phase 2: h = T @ seW2 + b2 + x, thread = one of 200 cols
    if (tid < DM_){
        int col = tid;
        float acc[8];
        float bb = seb2[col];
        #pragma unroll
        for (int r=0;r<8;++r) acc[r] = bb;
        #pragma unroll 4
        for (int k=0;k<DI_;++k){
            float w = seW2[(long)k*DM_ + col];         // coalesced 800B
            float4 t0 = *(const float4*)(&tT[k][0]);   // broadcast
            float4 t1 = *(const float4*)(&tT[k][4]);
            acc[0]+=t0.x*w; acc[1]+=t0.y*w; acc[2]+=t0.z*w; acc[3]+=t0.w*w;
            acc[4]+=t1.x*w; acc[5]+=t1.y*w; acc[6]+=t1.z*w; acc[7]+=t1.w*w;
        }
        #pragma unroll
        for (int r=0;r<8;++r) hv[r][col] = acc[r] + xT[col][r];
    }
    __syncthreads();

    // LayerNorm stats: wave w = row w (all 64 lanes active -> shfl safe)
    {
        int w = tid >> 6, l = tid & 63;
        float v0 = hv[w][l], v1 = hv[w][l+64], v2 = hv[w][l+128];
        float v3 = (l < 8) ? hv[w][l+192] : 0.f;
        float s1 = v0+v1+v2+v3;
        float s2 = v0*v0+v1*v1+v2*v2+v3*v3;
        #pragma unroll
        for (int o = 32; o; o >>= 1){ s1 += __shfl_down(s1, o); s2 += __shfl_down(s2, o); }
        if (l == 0){
            float mu = s1 * (1.f/DM_);
            mv[w][0] = mu;
            mv[w][1] = rsqrtf(s2 * (1.f/DM_) - mu*mu + 1e-5f);
        }
    }
    __syncthreads();
    {
        int w = tid >> 6, l = tid & 63;
        int row = r0 + w;
        if (row < 777){
            float mu = mv[w][0], rs = mv[w][1];
            float* out = (row < 768) ? qg + (long)row*DM_ : sEnc + (long)(row-768)*DM_;
            out[l]     = ln_g[l]    *(hv[w][l]    -mu)*rs + ln_b[l];
            out[l+64]  = ln_g[l+64] *(hv[w][l+64] -mu)*rs + ln_b[l+64];
            out[l+128] = ln_g[l+128]*(hv[w][l+128]-mu)*rs + ln_b[l+128];
            if (l < 8) out[l+192] = ln_g[l+192]*(hv[w][l+192]-mu)*rs + ln_b[l+192];
        }
    }
}

// ---------------------------------------------------------------------------
// Kernel 4: sw (+ sg).  grid = 75, 64 thr.
__global__ __launch_bounds__(64) void sw_kernel(
    const float* __restrict__ sEnc, const float* __restrict__ Whh,
    float* __restrict__ sg, float* __restrict__ sW)
{
    int b = blockIdx.x, tid = threadIdx.x;
    int s = b / 25, c0 = (b - s*25)*64;
    __shared__ float sgl[DM_];
    for (int j = tid; j < DM_; j += 64){
        float val = (sEnc[s*DM_ + j] + sEnc[(3+s)*DM_ + j] + sEnc[(6+s)*DM_ + j]) * (1.f/3.f);
        sgl[j] = val;
        if (c0 == 0) sg[s*DM_ + j] = val;
    }
    __syncthreads();
    int col = c0 + tid;
    float acc = 0.f;
    #pragma unroll 4
    for (int i = 0; i < DM_; ++i) acc += sgl[i] * Whh[(long)(DM_+i)*G4_ + col];
    sW[s*G4_ + col] = acc;
}

// ---------------------------------------------------------------------------
// Kernel 5: gemm (r5 proven): C[768x1600] = A[768x200] @ B[200x1600] + epilogue.
// mode 0: += bih+bhh.  mode 1: += qW0 + alpha·sW.  grid 600, 128 thr.
__global__ __launch_bounds__(128) void gemm_kernel(
    const float* __restrict__ A, const float* __restrict__ B,
    const float* __restrict__ qW0, const float* __restrict__ sW,
    const float* __restrict__ alpha,
    const float* __restrict__ bih, const float* __restrict__ bhh,
    float* __restrict__ C, int mode)
{
    int bx = blockIdx.x % 25, by = blockIdx.x / 25;
    int row0 = by*32, col0 = bx*64;
    int tid = threadIdx.x;

    __shared__ float As[50][32];
    __shared__ float Bs[50][64];
    __shared__ float alf[32][3];

    if (mode == 1 && tid < 96) alf[tid/3][tid%3] = alpha[(row0 + tid/3)*3 + tid%3];

    int tx = tid & 15, ty = tid >> 4;
    float acc[4][4] = {};

    for (int kt = 0; kt < 4; ++kt){
        for (int idx = tid; idx < 800; idx += 128){
            int r = idx & 31, p = idx >> 5;
            float2 a2 = *(const float2*)(A + (long)(row0+r)*DM_ + kt*50 + p*2);
            As[p*2][r] = a2.x; As[p*2+1][r] = a2.y;
        }
        for (int idx = tid; idx < 800; idx += 128){
            int k = idx >> 4, c4 = idx & 15;
            *(float4*)(&Bs[k][c4*4]) = *(const float4*)(B + (long)(kt*50+k)*G4_ + col0 + c4*4);
        }
        __syncthreads();
        #pragma unroll 2
        for (int k = 0; k < 50; ++k){
            float4 a = *(const float4*)(&As[k][ty*4]);
            float4 bq = *(const float4*)(&Bs[k][tx*4]);
            acc[0][0]+=a.x*bq.x; acc[0][1]+=a.x*bq.y; acc[0][2]+=a.x*bq.z; acc[0][3]+=a.x*bq.w;
            acc[1][0]+=a.y*bq.x; acc[1][1]+=a.y*bq.y; acc[1][2]+=a.y*bq.z; acc[1][3]+=a.y*bq.w;
            acc[2][0]+=a.z*bq.x; acc[2][1]+=a.z*bq.y; acc[2][2]+=a.z*bq.z; acc[2][3]+=a.z*bq.w;
            acc[3][0]+=a.w*bq.x; acc[3][1]+=a.w*bq.y; acc[3][2]+=a.w*bq.z; acc[3][3]+=a.w*bq.w;
        }
        __syncthreads();
    }

    int cc0 = col0 + tx*4;
    if (mode == 0){
        float4 u = *(const float4*)(bih + cc0);
        float4 w = *(const float4*)(bhh + cc0);
        float4 add = make_float4(u.x+w.x, u.y+w.y, u.z+w.z, u.w+w.w);
        #pragma unroll
        for (int r = 0; r < 4; ++r){
            int row = row0 + ty*4 + r;
            float4 o = make_float4(acc[r][0]+add.x, acc[r][1]+add.y, acc[r][2]+add.z, acc[r][3]+add.w);
            *(float4*)(C + (long)row*G4_ + cc0) = o;
        }
    } else {
        float4 s0 = *(const float4*)(sW + 0*G4_ + cc0);
        float4 s1 = *(const float4*)(sW + 1*G4_ + cc0);
        float4 s2 = *(const float4*)(sW + 2*G4_ + cc0);
        #pragma unroll
        for (int r = 0; r < 4; ++r){
            int row = row0 + ty*4 + r;
            float a0 = alf[ty*4+r][0], a1 = alf[ty*4+r][1], a2 = alf[ty*4+r][2];
            float4 qv = *(const float4*)(qW0 + (long)row*G4_ + cc0);
            float4 o;
            o.x = acc[r][0] + qv.x + a0*s0.x + a1*s1.x + a2*s2.x;
            o.y = acc[r][1] + qv.y + a0*s0.y + a1*s1.y + a2*s2.y;
            o.z = acc[r][2] + qv.z + a0*s0.z + a1*s1.z + a2*s2.z;
            o.w = acc[r][3] + qv.w + a0*s0.w + a1*s1.w + a2*s2.w;
            *(float4*)(C + (long)row*G4_ + cc0) = o;
        }
    }
}

// ---------------------------------------------------------------------------
// LSTM cell + support attention (r5 proven). grid 192 x 256 thr, 4 rows/block.
__global__ __launch_bounds__(256) void cell_kernel(
    const float* __restrict__ G, const float* __restrict__ qg,
    const float* __restrict__ sg, float* __restrict__ c,
    float* __restrict__ h, float* __restrict__ alpha, float* __restrict__ sAll,
    int first, int last)
{
    int b = blockIdx.x, tid = threadIdx.x;
    int row0 = b*4;
    __shared__ float hbuf[4][DM_];
    __shared__ float sup[600];
    __shared__ float lg[4][3];

    for (int i = tid; i < 600; i += 256) sup[i] = sg[i];

    for (int idx = tid; idx < 4*DI_; idx += 256){
        int r = idx / DI_, j = idx - r*DI_;
        int row = row0 + r;
        const float* g = G + (long)row*G4_;
        float gi = g[j], gf = g[DI_+j], gg = g[2*DI_+j];
        float cold = first ? 0.f : c[(long)row*DI_ + j];
        float c2 = sigf(gf)*cold + sigf(gi)*tanhf(gg);
        c[(long)row*DI_ + j] = c2;
        if (j < DM_){
            float go = g[3*DI_+j];
            float hval = qg[(long)row*DM_ + j] + sigf(go)*tanhf(c2);
            hbuf[r][j] = hval;
            h[(long)row*DM_ + j] = hval;
        }
    }
    __syncthreads();

    if (!last){
        if (tid < 192){
            int p = tid >> 4, l = tid & 15, r = p/3, s = p - r*3;
            float part = 0.f;
            for (int d = l; d < DM_; d += 16) part += hbuf[r][d]*sup[s*DM_+d];
            for (int o = 8; o; o >>= 1) part += __shfl_down(part, o, 16);
            if (!l) lg[r][s] = part;
        }
        __syncthreads();
        if (tid < 4){
            float l0 = lg[tid][0], l1 = lg[tid][1], l2 = lg[tid][2];
            float m = fmaxf(l0, fmaxf(l1, l2));
            float e0 = __expf(l0-m), e1 = __expf(l1-m), e2 = __expf(l2-m);
            float inv = 1.f/(e0+e1+e2);
            alpha[(row0+tid)*3+0] = e0*inv;
            alpha[(row0+tid)*3+1] = e1*inv;
            alpha[(row0+tid)*3+2] = e2*inv;
        }
    } else {
        int v = row0 >> 8;
        if (tid < 64){
            int r = tid >> 4, l = tid & 15;
            float part = 0.f;
            for (int d = l; d < DM_; d += 16) part += hbuf[r][d]*sup[v*DM_+d];
            for (int o = 8; o; o >>= 1) part += __shfl_down(part, o, 16);
            if (!l) sAll[row0+r] = part;
        }
    }
}

// ---------------------------------------------------------------------------
__global__ void final_kernel(const float* __restrict__ sAll, float* __restrict__ out){
    int n = blockIdx.x*blockDim.x + threadIdx.x;
    if (n < 256) out[n] = fmaxf(sAll[n], fmaxf(sAll[256+n], sAll[512+n]));
}

// ---------------------------------------------------------------------------
extern "C" void kernel_launch(void* const* d_in, const int* in_sizes, int n_in,
                              void* d_out, int out_size, void* d_ws, size_t ws_size,
                              hipStream_t stream)
{
    const float* ent_emb=(const float*)d_in[0];
    const float* rel_emb=(const float*)d_in[1];
    const float* W1=(const float*)d_in[2];  const float* b1=(const float*)d_in[3];
    const float* W2=(const float*)d_in[4];  const float* b2=(const float*)d_in[5];
    const float* W3=(const float*)d_in[6];  const float* b3=(const float*)d_in[7];
    const float* attW1=(const float*)d_in[8];
    const float* attW2=(const float*)d_in[10];
    const float* seW1=(const float*)d_in[12]; const float* seb1=(const float*)d_in[13];
    const float* seW2=(const float*)d_in[14]; const float* seb2=(const float*)d_in[15];
    const float* ln_g=(const float*)d_in[16]; const float* ln_b=(const float*)d_in[17];
    const float* Wih=(const float*)d_in[18];  const float* bih=(const float*)d_in[19];
    const float* Whh=(const float*)d_in[20];  const float* bhh=(const float*)d_in[21];
    const int* qlc_out=(const int*)d_in[24];  const int* qlc_in=(const int*)d_in[25];
    const int* qrc_out=(const int*)d_in[27];  const int* qrc_in=(const int*)d_in[28];
    const int* slc_out=(const int*)d_in[30];  const int* slc_in=(const int*)d_in[31];
    const int* src_out=(const int*)d_in[33];  const int* src_in=(const int*)d_in[34];

    float* ws = (float*)d_ws;
    // region A (first 1.5M floats), time-multiplexed:
    //   ent_bf (bf16, 750k float-slots): views -> neigh
    //   gates  (ws+0, 1228800):          LSTM steps
    unsigned short* ent_bf = (unsigned short*)ws;
    float* gates = ws;
    float* rs_in = ws + 1500000;       // 15,000
    float* rs_out= ws + 1515000;       // 15,000
    float* X     = ws + 1530000;       // 156,800 (784x200; neigh -> senc; then h)
    float* qg    = ws + 1686800;       // 153,600
    float* sEnc  = ws + 1840400;       // 1,800
    float* sg    = ws + 1842200;       // 600
    float* qW0   = ws + 1842800;       // 1,228,800
    float* cst   = ws + 3071600;       // 307,200
    float* alpha = ws + 3378800;       // 2,304
    float* sW    = ws + 3381104;       // 4,800
    float* sAll  = ws + 3385904;       // 768
    float* h     = X;                  // X dead after senc

    views_kernel<<<1250, 128, 0, stream>>>(ent_emb, rel_emb, W1,b1,W2,b2,W3,b3,
                                           attW1, attW2, ent_bf, rs_in, rs_out);
    neigh_kernel<<<dim3(518,3), 512, 0, stream>>>(qlc_out,qlc_in,qrc_out,qrc_in,
                                                  slc_out,slc_in,src_out,src_in,
                                                  ent_bf, rs_in, rs_out, X);
    senc_kernel<<<98, 512, 0, stream>>>(X, seW1, seb1, seW2, seb2,
                                        ln_g, ln_b, qg, sEnc);
    sw_kernel<<<75, 64, 0, stream>>>(sEnc, Whh, sg, sW);

    gemm_kernel<<<600, 128, 0, stream>>>(qg, Wih, nullptr, nullptr, nullptr,
                                         bih, bhh, qW0, 0);
    cell_kernel<<<192, 256, 0, stream>>>(qW0, qg, sg, cst, h, alpha, sAll, 1, 0);
    for (int s = 1; s < 4; ++s){
        gemm_kernel<<<600, 128, 0, stream>>>(h, Whh, qW0, sW, alpha,
                                             nullptr, nullptr, gates, 1);
        cell_kernel<<<192, 256, 0, stream>>>(gates, qg, sg, cst, h, alpha, sAll,
                                             0, (s==3) ? 1 : 0);
    }
    final_kernel<<<1, 256, 0, stream>>>(sAll, (float*)d_out);
}